// Round 1
// baseline (720.748 us; speedup 1.0000x reference)
//
#include <hip/hip_runtime.h>
#include <math.h>

// MARN cell, B=4096, IN_DIM=128, UNITS=256, NUM_K=64, NUM_S=256 (all fp32)
// Outputs (flat, in order): h (4096x256), c (4096x256), M_curr (4096x64x256), k_curr (4096x256)

#define BATCH 4096
#define INDIM 128
#define UNITS 256
#define NUMK  64
#define NUMS  256

__device__ __forceinline__ float sigf(float x) { return 1.0f / (1.0f + expf(-x)); }

// ---------------------------------------------------------------------------
// K1: gates GEMM  (xh @ {Wf,Wt,Wi,Wo} + b) -> c = f*c_prev + i*t, o stashed
// Tile: 64 rows x 64 cols x 4 gates per block, 256 threads, BK=16
// ---------------------------------------------------------------------------
__global__ __launch_bounds__(256) void k1_gates(
    const float* __restrict__ X, const float* __restrict__ h_prev,
    const float* __restrict__ c_prev,
    const float* __restrict__ Wf, const float* __restrict__ Wt,
    const float* __restrict__ Wi, const float* __restrict__ Wo,
    const float* __restrict__ bf, const float* __restrict__ bt,
    const float* __restrict__ bi, const float* __restrict__ bo,
    float* __restrict__ c_out, float* __restrict__ o_out)
{
    __shared__ float sA[16][68];       // xh tile [k][m], pad 68 -> conflict-free
    __shared__ float sB[4][16][68];    // per-gate W tile [k][n]

    const int t  = threadIdx.x;
    const int bm = blockIdx.x;   // 0..63 (rows)
    const int bn = blockIdx.y;   // 0..3  (64-col slice)

    float acc[4][4][4];
    #pragma unroll
    for (int g = 0; g < 4; ++g)
        #pragma unroll
        for (int mi = 0; mi < 4; ++mi)
            #pragma unroll
            for (int ni = 0; ni < 4; ++ni) acc[g][mi][ni] = 0.0f;

    const float* Wg[4] = {Wf, Wt, Wi, Wo};

    const int m0 = (t & 15) * 4;   // compute: 4 rows
    const int n0 = (t >> 4) * 4;   // compute: 4 cols
    const int lm  = t >> 2;        // A-load: row within tile
    const int lk  = (t & 3) * 4;   // A-load: k group (float4)
    const int lbk = t >> 4;        // B-load: k row
    const int lbc = (t & 15) * 4;  // B-load: col group (float4)

    for (int k0 = 0; k0 < 384; k0 += 16) {
        // stage A (xh = [X | h_prev])
        {
            const int row = bm * 64 + lm;
            const int gk = k0 + lk;
            float4 av;
            if (gk < INDIM) av = *(const float4*)(X + row * INDIM + gk);
            else            av = *(const float4*)(h_prev + row * UNITS + (gk - INDIM));
            sA[lk + 0][lm] = av.x; sA[lk + 1][lm] = av.y;
            sA[lk + 2][lm] = av.z; sA[lk + 3][lm] = av.w;
        }
        // stage B (4 gate weight tiles)
        #pragma unroll
        for (int g = 0; g < 4; ++g) {
            float4 bv = *(const float4*)(Wg[g] + (k0 + lbk) * UNITS + bn * 64 + lbc);
            *(float4*)&sB[g][lbk][lbc] = bv;
        }
        __syncthreads();
        #pragma unroll
        for (int k = 0; k < 16; ++k) {
            float a[4];
            *(float4*)a = *(float4*)&sA[k][m0];
            #pragma unroll
            for (int g = 0; g < 4; ++g) {
                float b[4];
                *(float4*)b = *(float4*)&sB[g][k][n0];
                #pragma unroll
                for (int mi = 0; mi < 4; ++mi)
                    #pragma unroll
                    for (int ni = 0; ni < 4; ++ni)
                        acc[g][mi][ni] = fmaf(a[mi], b[ni], acc[g][mi][ni]);
            }
        }
        __syncthreads();
    }

    const int col0 = bn * 64 + n0;
    const int row0 = bm * 64 + m0;
    float bfv[4], btv[4], biv[4], bov[4];
    *(float4*)bfv = *(const float4*)(bf + col0);
    *(float4*)btv = *(const float4*)(bt + col0);
    *(float4*)biv = *(const float4*)(bi + col0);
    *(float4*)bov = *(const float4*)(bo + col0);
    #pragma unroll
    for (int mi = 0; mi < 4; ++mi) {
        const int row = row0 + mi;
        float cp[4];
        *(float4*)cp = *(const float4*)(c_prev + row * UNITS + col0);
        float cv[4], ov[4];
        #pragma unroll
        for (int ni = 0; ni < 4; ++ni) {
            float fv = sigf(acc[0][mi][ni] + bfv[ni]);
            float tv = sigf(acc[1][mi][ni] + btv[ni]);
            float iv = sigf(acc[2][mi][ni] + biv[ni]);
            float oo = sigf(acc[3][mi][ni] + bov[ni]);
            cv[ni] = fv * cp[ni] + iv * tv;
            ov[ni] = oo;
        }
        *(float4*)(c_out + row * UNITS + col0) = *(float4*)cv;
        *(float4*)(o_out + row * UNITS + col0) = *(float4*)ov;
    }
}

// ---------------------------------------------------------------------------
// K2: cos -> softmax(alpha) -> r.  One block (4 waves) per batch row.
// M row (64x256) read ONCE from HBM into registers (16 float4/thread).
// ---------------------------------------------------------------------------
__global__ __launch_bounds__(256) void k2_cosr(
    const float* __restrict__ M, const float* __restrict__ k_prev,
    float* __restrict__ alpha_out, float* __restrict__ r_out)
{
    const int b = blockIdx.x;
    const int t = threadIdx.x;
    const int lane = t & 63;
    const int w = t >> 6;

    __shared__ float scos[64];
    __shared__ float salpha[64];
    __shared__ float spr[4][256];

    // k_prev segment for this lane (all 4 waves load the same values; L1 hit)
    const float4 k4 = *(const float4*)(k_prev + b * NUMS + lane * 4);
    float kss = k4.x * k4.x + k4.y * k4.y + k4.z * k4.z + k4.w * k4.w;
    #pragma unroll
    for (int m = 1; m < 64; m <<= 1) kss += __shfl_xor(kss, m, 64);
    const float knorm = sqrtf(fmaxf(kss, 1e-12f));

    // load 16 M rows per wave into registers
    const float* Mb = M + (size_t)b * (NUMK * NUMS);
    float4 mreg[16];
    #pragma unroll
    for (int j = 0; j < 16; ++j)
        mreg[j] = *(const float4*)(Mb + (w * 16 + j) * NUMS + lane * 4);

    // cos per row
    #pragma unroll
    for (int j = 0; j < 16; ++j) {
        const float4 m4 = mreg[j];
        float dot = m4.x * k4.x + m4.y * k4.y + m4.z * k4.z + m4.w * k4.w;
        float ssq = m4.x * m4.x + m4.y * m4.y + m4.z * m4.z + m4.w * m4.w;
        #pragma unroll
        for (int m = 1; m < 64; m <<= 1) {
            dot += __shfl_xor(dot, m, 64);
            ssq += __shfl_xor(ssq, m, 64);
        }
        if (lane == 0) {
            const float mnorm = sqrtf(fmaxf(ssq, 1e-12f));
            scos[w * 16 + j] = dot / (mnorm * knorm);
        }
    }
    __syncthreads();

    // softmax(-cos) over 64 entries (wave 0)
    if (t < 64) {
        float v = -scos[t];
        float vmax = v;
        #pragma unroll
        for (int m = 1; m < 64; m <<= 1) vmax = fmaxf(vmax, __shfl_xor(vmax, m, 64));
        float e = expf(v - vmax);
        float s = e;
        #pragma unroll
        for (int m = 1; m < 64; m <<= 1) s += __shfl_xor(s, m, 64);
        const float al = e / s;
        salpha[t] = al;
        alpha_out[b * NUMK + t] = al;
    }
    __syncthreads();

    // r = sum_k alpha_k * M[k,:]  (per-wave partial from registers)
    float pr0 = 0.f, pr1 = 0.f, pr2 = 0.f, pr3 = 0.f;
    #pragma unroll
    for (int j = 0; j < 16; ++j) {
        const float al = salpha[w * 16 + j];
        pr0 = fmaf(al, mreg[j].x, pr0);
        pr1 = fmaf(al, mreg[j].y, pr1);
        pr2 = fmaf(al, mreg[j].z, pr2);
        pr3 = fmaf(al, mreg[j].w, pr3);
    }
    *(float4*)&spr[w][lane * 4] = make_float4(pr0, pr1, pr2, pr3);
    __syncthreads();
    const float rv = spr[0][t] + spr[1][t] + spr[2][t] + spr[3][t];
    r_out[b * NUMS + t] = rv;
}

// ---------------------------------------------------------------------------
// K3: rc1 = sig(r@Wr + c@Wc); h = o * tanh(c + rc1*(r@Wh))
// ---------------------------------------------------------------------------
__global__ __launch_bounds__(256) void k3_h(
    const float* __restrict__ r, const float* __restrict__ c,
    const float* __restrict__ o,
    const float* __restrict__ Wr, const float* __restrict__ Wc,
    const float* __restrict__ Wh,
    float* __restrict__ h_out)
{
    __shared__ float sAr[16][68];
    __shared__ float sAc[16][68];
    __shared__ float sB[3][16][68];

    const int t  = threadIdx.x;
    const int bm = blockIdx.x;
    const int bn = blockIdx.y;

    float acc[3][4][4];
    #pragma unroll
    for (int g = 0; g < 3; ++g)
        #pragma unroll
        for (int mi = 0; mi < 4; ++mi)
            #pragma unroll
            for (int ni = 0; ni < 4; ++ni) acc[g][mi][ni] = 0.0f;

    const float* Wg[3] = {Wr, Wc, Wh};
    const int m0 = (t & 15) * 4;
    const int n0 = (t >> 4) * 4;
    const int lm  = t >> 2;
    const int lk  = (t & 3) * 4;
    const int lbk = t >> 4;
    const int lbc = (t & 15) * 4;

    for (int k0 = 0; k0 < 256; k0 += 16) {
        {
            const int row = bm * 64 + lm;
            float4 rv = *(const float4*)(r + row * UNITS + k0 + lk);
            float4 cv = *(const float4*)(c + row * UNITS + k0 + lk);
            sAr[lk + 0][lm] = rv.x; sAr[lk + 1][lm] = rv.y;
            sAr[lk + 2][lm] = rv.z; sAr[lk + 3][lm] = rv.w;
            sAc[lk + 0][lm] = cv.x; sAc[lk + 1][lm] = cv.y;
            sAc[lk + 2][lm] = cv.z; sAc[lk + 3][lm] = cv.w;
        }
        #pragma unroll
        for (int g = 0; g < 3; ++g) {
            float4 bv = *(const float4*)(Wg[g] + (k0 + lbk) * UNITS + bn * 64 + lbc);
            *(float4*)&sB[g][lbk][lbc] = bv;
        }
        __syncthreads();
        #pragma unroll
        for (int k = 0; k < 16; ++k) {
            float ar[4], ac[4];
            *(float4*)ar = *(float4*)&sAr[k][m0];
            *(float4*)ac = *(float4*)&sAc[k][m0];
            float b0[4], b1[4], b2[4];
            *(float4*)b0 = *(float4*)&sB[0][k][n0];
            *(float4*)b1 = *(float4*)&sB[1][k][n0];
            *(float4*)b2 = *(float4*)&sB[2][k][n0];
            #pragma unroll
            for (int mi = 0; mi < 4; ++mi)
                #pragma unroll
                for (int ni = 0; ni < 4; ++ni) {
                    acc[0][mi][ni] = fmaf(ar[mi], b0[ni], acc[0][mi][ni]);
                    acc[1][mi][ni] = fmaf(ac[mi], b1[ni], acc[1][mi][ni]);
                    acc[2][mi][ni] = fmaf(ar[mi], b2[ni], acc[2][mi][ni]);
                }
        }
        __syncthreads();
    }

    const int col0 = bn * 64 + n0;
    const int row0 = bm * 64 + m0;
    #pragma unroll
    for (int mi = 0; mi < 4; ++mi) {
        const int row = row0 + mi;
        float cv[4], ov[4], hv[4];
        *(float4*)cv = *(const float4*)(c + row * UNITS + col0);
        *(float4*)ov = *(const float4*)(o + row * UNITS + col0);
        #pragma unroll
        for (int ni = 0; ni < 4; ++ni) {
            const float rc1 = sigf(acc[0][mi][ni] + acc[1][mi][ni]);
            hv[ni] = ov[ni] * tanhf(cv[ni] + rc1 * acc[2][mi][ni]);
        }
        *(float4*)(h_out + row * UNITS + col0) = *(float4*)hv;
    }
}

// ---------------------------------------------------------------------------
// K4: k_curr = tanh(h@Wk+bk); e = sig(h@We+be); a = tanh(h@Wa+ba)
// ---------------------------------------------------------------------------
__global__ __launch_bounds__(256) void k4_kea(
    const float* __restrict__ h,
    const float* __restrict__ Wk, const float* __restrict__ We,
    const float* __restrict__ Wa,
    const float* __restrict__ bk, const float* __restrict__ be,
    const float* __restrict__ ba,
    float* __restrict__ k_out, float* __restrict__ e_out, float* __restrict__ a_out)
{
    __shared__ float sA[16][68];
    __shared__ float sB[3][16][68];

    const int t  = threadIdx.x;
    const int bm = blockIdx.x;
    const int bn = blockIdx.y;

    float acc[3][4][4];
    #pragma unroll
    for (int g = 0; g < 3; ++g)
        #pragma unroll
        for (int mi = 0; mi < 4; ++mi)
            #pragma unroll
            for (int ni = 0; ni < 4; ++ni) acc[g][mi][ni] = 0.0f;

    const float* Wg[3] = {Wk, We, Wa};
    const int m0 = (t & 15) * 4;
    const int n0 = (t >> 4) * 4;
    const int lm  = t >> 2;
    const int lk  = (t & 3) * 4;
    const int lbk = t >> 4;
    const int lbc = (t & 15) * 4;

    for (int k0 = 0; k0 < 256; k0 += 16) {
        {
            const int row = bm * 64 + lm;
            float4 av = *(const float4*)(h + row * UNITS + k0 + lk);
            sA[lk + 0][lm] = av.x; sA[lk + 1][lm] = av.y;
            sA[lk + 2][lm] = av.z; sA[lk + 3][lm] = av.w;
        }
        #pragma unroll
        for (int g = 0; g < 3; ++g) {
            float4 bv = *(const float4*)(Wg[g] + (k0 + lbk) * UNITS + bn * 64 + lbc);
            *(float4*)&sB[g][lbk][lbc] = bv;
        }
        __syncthreads();
        #pragma unroll
        for (int k = 0; k < 16; ++k) {
            float a[4];
            *(float4*)a = *(float4*)&sA[k][m0];
            float b0[4], b1[4], b2[4];
            *(float4*)b0 = *(float4*)&sB[0][k][n0];
            *(float4*)b1 = *(float4*)&sB[1][k][n0];
            *(float4*)b2 = *(float4*)&sB[2][k][n0];
            #pragma unroll
            for (int mi = 0; mi < 4; ++mi)
                #pragma unroll
                for (int ni = 0; ni < 4; ++ni) {
                    acc[0][mi][ni] = fmaf(a[mi], b0[ni], acc[0][mi][ni]);
                    acc[1][mi][ni] = fmaf(a[mi], b1[ni], acc[1][mi][ni]);
                    acc[2][mi][ni] = fmaf(a[mi], b2[ni], acc[2][mi][ni]);
                }
        }
        __syncthreads();
    }

    const int col0 = bn * 64 + n0;
    const int row0 = bm * 64 + m0;
    float bkv[4], bev[4], bav[4];
    *(float4*)bkv = *(const float4*)(bk + col0);
    *(float4*)bev = *(const float4*)(be + col0);
    *(float4*)bav = *(const float4*)(ba + col0);
    #pragma unroll
    for (int mi = 0; mi < 4; ++mi) {
        const int row = row0 + mi;
        float kv[4], ev[4], av[4];
        #pragma unroll
        for (int ni = 0; ni < 4; ++ni) {
            kv[ni] = tanhf(acc[0][mi][ni] + bkv[ni]);
            ev[ni] = sigf (acc[1][mi][ni] + bev[ni]);
            av[ni] = tanhf(acc[2][mi][ni] + bav[ni]);
        }
        *(float4*)(k_out + row * UNITS + col0) = *(float4*)kv;
        *(float4*)(e_out + row * UNITS + col0) = *(float4*)ev;
        *(float4*)(a_out + row * UNITS + col0) = *(float4*)av;
    }
}

// ---------------------------------------------------------------------------
// K5: M_curr = M_prev*(1 - alpha*e) + alpha*a   (streaming, float4)
// One block per batch row; alpha in LDS, e/a in registers.
// ---------------------------------------------------------------------------
__global__ __launch_bounds__(256) void k5_mup(
    const float* __restrict__ M, const float* __restrict__ alpha,
    const float* __restrict__ e, const float* __restrict__ a,
    float* __restrict__ Mout)
{
    const int b = blockIdx.x;
    const int t = threadIdx.x;
    __shared__ float sal[64];
    if (t < 64) sal[t] = alpha[b * NUMK + t];

    const int s4 = (t & 63) * 4;
    const int kr = t >> 6;
    const float4 e4 = *(const float4*)(e + b * NUMS + s4);
    const float4 a4 = *(const float4*)(a + b * NUMS + s4);
    __syncthreads();

    const float* Mb = M + (size_t)b * (NUMK * NUMS);
    float* Ob = Mout + (size_t)b * (NUMK * NUMS);
    #pragma unroll
    for (int j = 0; j < 16; ++j) {
        const int k = j * 4 + kr;
        const float al = sal[k];
        float4 m4 = *(const float4*)(Mb + k * NUMS + s4);
        float4 o4;
        o4.x = m4.x * (1.0f - al * e4.x) + al * a4.x;
        o4.y = m4.y * (1.0f - al * e4.y) + al * a4.y;
        o4.z = m4.z * (1.0f - al * e4.z) + al * a4.z;
        o4.w = m4.w * (1.0f - al * e4.w) + al * a4.w;
        *(float4*)(Ob + k * NUMS + s4) = o4;
    }
}

// ---------------------------------------------------------------------------
extern "C" void kernel_launch(void* const* d_in, const int* in_sizes, int n_in,
                              void* d_out, int out_size, void* d_ws, size_t ws_size,
                              hipStream_t stream)
{
    (void)in_sizes; (void)n_in; (void)out_size; (void)ws_size;

    const float* X      = (const float*)d_in[0];
    const float* h_prev = (const float*)d_in[1];
    const float* c_prev = (const float*)d_in[2];
    const float* M_prev = (const float*)d_in[3];
    const float* k_prev = (const float*)d_in[4];
    const float* Wf = (const float*)d_in[5];
    const float* Wt = (const float*)d_in[6];
    const float* Wi = (const float*)d_in[7];
    const float* Wo = (const float*)d_in[8];
    const float* bf = (const float*)d_in[9];
    const float* bt = (const float*)d_in[10];
    const float* bi = (const float*)d_in[11];
    const float* bo = (const float*)d_in[12];
    const float* Wk = (const float*)d_in[13];
    const float* bk = (const float*)d_in[14];
    const float* Wr = (const float*)d_in[15];
    const float* Wc = (const float*)d_in[16];
    const float* Wh = (const float*)d_in[17];
    const float* We = (const float*)d_in[18];
    const float* be = (const float*)d_in[19];
    const float* Wa = (const float*)d_in[20];
    const float* ba = (const float*)d_in[21];

    float* out = (float*)d_out;
    float* h_out = out;                       // 4096*256
    float* c_out = out + 1048576;             // 4096*256
    float* M_out = out + 2097152;             // 4096*64*256
    float* k_out = out + 69206016;            // 4096*256

    float* ws    = (float*)d_ws;
    float* o_ws  = ws;                        // 4096*256
    float* al_ws = ws + 1048576;              // 4096*64
    float* r_ws  = ws + 1310720;              // 4096*256
    float* e_ws  = ws + 2359296;              // 4096*256
    float* a_ws  = ws + 3407872;              // 4096*256

    k1_gates<<<dim3(64, 4), 256, 0, stream>>>(X, h_prev, c_prev,
                                              Wf, Wt, Wi, Wo, bf, bt, bi, bo,
                                              c_out, o_ws);
    k2_cosr<<<dim3(4096), 256, 0, stream>>>(M_prev, k_prev, al_ws, r_ws);
    k3_h<<<dim3(64, 4), 256, 0, stream>>>(r_ws, c_out, o_ws, Wr, Wc, Wh, h_out);
    k4_kea<<<dim3(64, 4), 256, 0, stream>>>(h_out, Wk, We, Wa, bk, be, ba,
                                            k_out, e_ws, a_ws);
    k5_mup<<<dim3(4096), 256, 0, stream>>>(M_prev, al_ws, e_ws, a_ws, M_out);
}

// Round 3
// 681.288 us; speedup vs baseline: 1.0579x; 1.0579x over previous
//
#include <hip/hip_runtime.h>
#include <math.h>

// MARN cell, B=4096, IN_DIM=128, UNITS=256, NUM_K=64, NUM_S=256 (all fp32)
// Outputs flat: h (4096x256), c (4096x256), M (4096x64x256), k (4096x256)

#define BATCH 4096
#define INDIM 128
#define UNITS 256
#define NUMK  64
#define NUMS  256

typedef unsigned short u16;
typedef __attribute__((ext_vector_type(4))) float  f32x4;
typedef __attribute__((ext_vector_type(8))) short  s16x8;   // 8 bf16 (4 VGPRs) MFMA frag
typedef __attribute__((ext_vector_type(4))) u16    u16x4;
typedef __attribute__((ext_vector_type(8))) u16    u16x8;

__device__ __forceinline__ float sigf(float x) { return 1.0f / (1.0f + expf(-x)); }

// round-to-nearest-even f32 -> bf16 bits
__device__ __forceinline__ u16 f2bf(float x) {
    unsigned u = __float_as_uint(x);
    return (u16)((u + 0x7fffu + ((u >> 16) & 1u)) >> 16);
}
__device__ __forceinline__ float bf2f(u16 h) {
    return __uint_as_float(((unsigned)h) << 16);
}
__device__ __forceinline__ void split_bf(float x, u16& hi, u16& lo) {
    hi = f2bf(x);
    lo = f2bf(x - bf2f(hi));
}

// ---------------------------------------------------------------------------
// prep_a1: xh = [X | h_prev] -> bf16 hi/lo [4096][384]
// ---------------------------------------------------------------------------
__global__ __launch_bounds__(256) void prep_a1(
    const float* __restrict__ X, const float* __restrict__ hp,
    u16* __restrict__ Ahi, u16* __restrict__ Alo)
{
    const int idx = blockIdx.x * 256 + threadIdx.x;   // 4096*96 groups
    const int row = idx / 96;
    const int cg  = (idx - row * 96) * 4;
    float4 v;
    if (cg < INDIM) v = *(const float4*)(X + row * INDIM + cg);
    else            v = *(const float4*)(hp + row * UNITS + (cg - INDIM));
    u16x4 h, l;
    u16 th, tl;
    split_bf(v.x, th, tl); h.x = th; l.x = tl;
    split_bf(v.y, th, tl); h.y = th; l.y = tl;
    split_bf(v.z, th, tl); h.z = th; l.z = tl;
    split_bf(v.w, th, tl); h.w = th; l.w = tl;
    *(u16x4*)(Ahi + row * 384 + cg) = h;
    *(u16x4*)(Alo + row * 384 + cg) = l;
}

// ---------------------------------------------------------------------------
// weight packers: W[K][256] -> Wt[Nout][K] bf16 hi/lo (transposed, gate-stacked)
// ---------------------------------------------------------------------------
__global__ __launch_bounds__(256) void pack_w1(
    const float* __restrict__ Wf, const float* __restrict__ Wt,
    const float* __restrict__ Wi, const float* __restrict__ Wo,
    u16* __restrict__ Whi, u16* __restrict__ Wlo)
{
    const int tid = blockIdx.x * 256 + threadIdx.x;   // 1024*48
    const int n  = tid / 48;
    const int k0 = (tid - n * 48) * 8;
    const float* src = (n < 256) ? Wf : (n < 512) ? Wt : (n < 768) ? Wi : Wo;
    const int nc = n & 255;
    u16x8 h, l;
    #pragma unroll
    for (int j = 0; j < 8; ++j) {
        float x = src[(k0 + j) * 256 + nc];
        u16 th, tl;
        split_bf(x, th, tl);
        h[j] = th; l[j] = tl;
    }
    *(u16x8*)(Whi + n * 384 + k0) = h;
    *(u16x8*)(Wlo + n * 384 + k0) = l;
}

// W3t [512][512]: rows 0..255: [Wr;Wc] col n ; rows 256..511: [Wh;0] col n-256
__global__ __launch_bounds__(256) void pack_w3(
    const float* __restrict__ Wr, const float* __restrict__ Wc,
    const float* __restrict__ Wh,
    u16* __restrict__ Whi, u16* __restrict__ Wlo)
{
    const int tid = blockIdx.x * 256 + threadIdx.x;   // 512*64
    const int n  = tid / 64;
    const int k0 = (tid - n * 64) * 8;
    u16x8 h, l;
    #pragma unroll
    for (int j = 0; j < 8; ++j) {
        const int k = k0 + j;
        float x;
        if (n < 256) x = (k < 256) ? Wr[k * 256 + n] : Wc[(k - 256) * 256 + n];
        else         x = (k < 256) ? Wh[k * 256 + (n - 256)] : 0.0f;
        u16 th, tl;
        split_bf(x, th, tl);
        h[j] = th; l[j] = tl;
    }
    *(u16x8*)(Whi + n * 512 + k0) = h;
    *(u16x8*)(Wlo + n * 512 + k0) = l;
}

__global__ __launch_bounds__(256) void pack_w4(
    const float* __restrict__ Wk, const float* __restrict__ We,
    const float* __restrict__ Wa,
    u16* __restrict__ Whi, u16* __restrict__ Wlo)
{
    const int tid = blockIdx.x * 256 + threadIdx.x;   // 768*32
    const int n  = tid / 32;
    const int k0 = (tid - n * 32) * 8;
    const float* src = (n < 256) ? Wk : (n < 512) ? We : Wa;
    const int nc = n & 255;
    u16x8 h, l;
    #pragma unroll
    for (int j = 0; j < 8; ++j) {
        float x = src[(k0 + j) * 256 + nc];
        u16 th, tl;
        split_bf(x, th, tl);
        h[j] = th; l[j] = tl;
    }
    *(u16x8*)(Whi + n * 256 + k0) = h;
    *(u16x8*)(Wlo + n * 256 + k0) = l;
}

// ---------------------------------------------------------------------------
// Generic MFMA GEMM: C[M][N] f32 = A[M][K] @ Bt[N][K]^T, bf16 hi/lo split
// (3 MFMAs: hh + lh + hl ~ fp32 accuracy). Direct-global fragments, no LDS.
// block 256 = 4 waves; wave tile 16 x 64; block tile 64 x 64.
// MFMA 16x16x32_bf16: A lane l: row l&15, k = (l>>4)*8..+8 (contiguous)
//                     C lane l: col l&15, row (l>>4)*4 + reg   [m89]
// ---------------------------------------------------------------------------
template<int K>
__global__ __launch_bounds__(256) void gemm_bf16x2(
    const u16* __restrict__ Ahi, const u16* __restrict__ Alo,
    const u16* __restrict__ Bhi, const u16* __restrict__ Blo,
    float* __restrict__ C, int N)
{
    const int t = threadIdx.x;
    const int wave = t >> 6, lane = t & 63;
    const int m0 = blockIdx.x * 64 + wave * 16;
    const int n0 = blockIdx.y * 64;
    const int r = lane & 15, g = lane >> 4;

    const u16* pAh = Ahi + (size_t)(m0 + r) * K + g * 8;
    const u16* pAl = Alo + (size_t)(m0 + r) * K + g * 8;
    const u16* pBh = Bhi + (size_t)(n0 + r) * K + g * 8;
    const u16* pBl = Blo + (size_t)(n0 + r) * K + g * 8;

    f32x4 acc[4];
    #pragma unroll
    for (int j = 0; j < 4; ++j) acc[j] = (f32x4){0.f, 0.f, 0.f, 0.f};

    #pragma unroll 2
    for (int k0 = 0; k0 < K; k0 += 32) {
        s16x8 ah = *(const s16x8*)(pAh + k0);
        s16x8 al = *(const s16x8*)(pAl + k0);
        #pragma unroll
        for (int j = 0; j < 4; ++j) {
            s16x8 bh = *(const s16x8*)(pBh + (size_t)j * 16 * K + k0);
            s16x8 bl = *(const s16x8*)(pBl + (size_t)j * 16 * K + k0);
            acc[j] = __builtin_amdgcn_mfma_f32_16x16x32_bf16(ah, bh, acc[j], 0, 0, 0);
            acc[j] = __builtin_amdgcn_mfma_f32_16x16x32_bf16(al, bh, acc[j], 0, 0, 0);
            acc[j] = __builtin_amdgcn_mfma_f32_16x16x32_bf16(ah, bl, acc[j], 0, 0, 0);
        }
    }

    #pragma unroll
    for (int j = 0; j < 4; ++j)
        #pragma unroll
        for (int rr = 0; rr < 4; ++rr)
            C[(size_t)(m0 + g * 4 + rr) * N + (n0 + j * 16 + r)] = acc[j][rr];
}

// ---------------------------------------------------------------------------
// e1: gates -> c = sig(f)*c_prev + sig(i)*sig(t); stash o; c also as bf16 hi/lo
// ---------------------------------------------------------------------------
__global__ __launch_bounds__(256) void e1(
    const float* __restrict__ G1, const float* __restrict__ c_prev,
    const float* __restrict__ bf, const float* __restrict__ bt,
    const float* __restrict__ bi, const float* __restrict__ bo,
    float* __restrict__ c_out, u16* __restrict__ A3hi, u16* __restrict__ A3lo,
    float* __restrict__ o_ws)
{
    const int idx = blockIdx.x * 256 + threadIdx.x;   // 4096*64
    const int row = idx >> 6;
    const int c0  = (idx & 63) * 4;
    const float* g = G1 + (size_t)row * 1024 + c0;
    float4 fv = *(const float4*)(g);
    float4 tv = *(const float4*)(g + 256);
    float4 iv = *(const float4*)(g + 512);
    float4 ov = *(const float4*)(g + 768);
    float4 bfv = *(const float4*)(bf + c0), btv = *(const float4*)(bt + c0);
    float4 biv = *(const float4*)(bi + c0), bov = *(const float4*)(bo + c0);
    float4 cp = *(const float4*)(c_prev + (size_t)row * 256 + c0);
    float fa[4] = {fv.x, fv.y, fv.z, fv.w}, ta[4] = {tv.x, tv.y, tv.z, tv.w};
    float ia[4] = {iv.x, iv.y, iv.z, iv.w}, oa[4] = {ov.x, ov.y, ov.z, ov.w};
    float ba_f[4] = {bfv.x, bfv.y, bfv.z, bfv.w}, ba_t[4] = {btv.x, btv.y, btv.z, btv.w};
    float ba_i[4] = {biv.x, biv.y, biv.z, biv.w}, ba_o[4] = {bov.x, bov.y, bov.z, bov.w};
    float cpa[4] = {cp.x, cp.y, cp.z, cp.w};
    float cv[4], oo[4];
    u16x4 chi, clo;
    #pragma unroll
    for (int j = 0; j < 4; ++j) {
        float f = sigf(fa[j] + ba_f[j]);
        float tt = sigf(ta[j] + ba_t[j]);
        float i = sigf(ia[j] + ba_i[j]);
        oo[j] = sigf(oa[j] + ba_o[j]);
        cv[j] = f * cpa[j] + i * tt;
        u16 th, tl;
        split_bf(cv[j], th, tl);
        chi[j] = th; clo[j] = tl;
    }
    *(float4*)(c_out + (size_t)row * 256 + c0) = make_float4(cv[0], cv[1], cv[2], cv[3]);
    *(float4*)(o_ws + (size_t)row * 256 + c0) = make_float4(oo[0], oo[1], oo[2], oo[3]);
    *(u16x4*)(A3hi + (size_t)row * 512 + 256 + c0) = chi;
    *(u16x4*)(A3lo + (size_t)row * 512 + 256 + c0) = clo;
}

// ---------------------------------------------------------------------------
// K2: cos -> softmax(alpha) -> r (bf16 hi/lo into A3). One block per batch row.
// ---------------------------------------------------------------------------
__global__ __launch_bounds__(256) void k2_cosr(
    const float* __restrict__ M, const float* __restrict__ k_prev,
    float* __restrict__ alpha_out, u16* __restrict__ A3hi, u16* __restrict__ A3lo)
{
    const int b = blockIdx.x;
    const int t = threadIdx.x;
    const int lane = t & 63;
    const int w = t >> 6;

    __shared__ float sdot[64][8];
    __shared__ float sssq[64][8];
    __shared__ float salpha[64];
    __shared__ float spr[4][256];

    const float4 k4 = *(const float4*)(k_prev + b * NUMS + lane * 4);
    float kss = k4.x * k4.x + k4.y * k4.y + k4.z * k4.z + k4.w * k4.w;
    #pragma unroll
    for (int m = 1; m < 64; m <<= 1) kss += __shfl_xor(kss, m, 64);
    const float knorm = sqrtf(fmaxf(kss, 1e-12f));

    const float* Mb = M + (size_t)b * (NUMK * NUMS);
    f32x4 mreg[16];
    #pragma unroll
    for (int j = 0; j < 16; ++j)
        mreg[j] = __builtin_nontemporal_load((const f32x4*)(Mb + (w * 16 + j) * NUMS + lane * 4));

    #pragma unroll
    for (int j = 0; j < 16; ++j) {
        const f32x4 m4 = mreg[j];
        float dot = m4.x * k4.x + m4.y * k4.y + m4.z * k4.z + m4.w * k4.w;
        float ssq = m4.x * m4.x + m4.y * m4.y + m4.z * m4.z + m4.w * m4.w;
        #pragma unroll
        for (int m = 1; m < 8; m <<= 1) {      // 3-step: 8-lane partials
            dot += __shfl_xor(dot, m, 64);
            ssq += __shfl_xor(ssq, m, 64);
        }
        if ((lane & 7) == 0) {
            sdot[w * 16 + j][lane >> 3] = dot;
            sssq[w * 16 + j][lane >> 3] = ssq;
        }
    }
    __syncthreads();

    if (t < 64) {
        float dot = 0.f, ssq = 0.f;
        #pragma unroll
        for (int q = 0; q < 8; ++q) { dot += sdot[t][q]; ssq += sssq[t][q]; }
        const float cosv = dot / (sqrtf(fmaxf(ssq, 1e-12f)) * knorm);
        float v = -cosv;
        float vmax = v;
        #pragma unroll
        for (int m = 1; m < 64; m <<= 1) vmax = fmaxf(vmax, __shfl_xor(vmax, m, 64));
        float e = expf(v - vmax);
        float s = e;
        #pragma unroll
        for (int m = 1; m < 64; m <<= 1) s += __shfl_xor(s, m, 64);
        const float al = e / s;
        salpha[t] = al;
        alpha_out[b * NUMK + t] = al;
    }
    __syncthreads();

    float pr0 = 0.f, pr1 = 0.f, pr2 = 0.f, pr3 = 0.f;
    #pragma unroll
    for (int j = 0; j < 16; ++j) {
        const float al = salpha[w * 16 + j];
        pr0 = fmaf(al, mreg[j].x, pr0);
        pr1 = fmaf(al, mreg[j].y, pr1);
        pr2 = fmaf(al, mreg[j].z, pr2);
        pr3 = fmaf(al, mreg[j].w, pr3);
    }
    *(float4*)&spr[w][lane * 4] = make_float4(pr0, pr1, pr2, pr3);
    __syncthreads();
    const float rv = spr[0][t] + spr[1][t] + spr[2][t] + spr[3][t];
    u16 hi, lo;
    split_bf(rv, hi, lo);
    A3hi[(size_t)b * 512 + t] = hi;
    A3lo[(size_t)b * 512 + t] = lo;
}

// ---------------------------------------------------------------------------
// e2: h = o * tanh(c + sig(rc_pre) * rh);  h also as bf16 hi/lo (A4)
// ---------------------------------------------------------------------------
__global__ __launch_bounds__(256) void e2(
    const float* __restrict__ G3, const float* __restrict__ c,
    const float* __restrict__ o,
    float* __restrict__ h_out, u16* __restrict__ A4hi, u16* __restrict__ A4lo)
{
    const int idx = blockIdx.x * 256 + threadIdx.x;   // 4096*64
    const int row = idx >> 6;
    const int c0  = (idx & 63) * 4;
    float4 rc = *(const float4*)(G3 + (size_t)row * 512 + c0);
    float4 rh = *(const float4*)(G3 + (size_t)row * 512 + 256 + c0);
    float4 cv = *(const float4*)(c + (size_t)row * 256 + c0);
    float4 ov = *(const float4*)(o + (size_t)row * 256 + c0);
    float rca[4] = {rc.x, rc.y, rc.z, rc.w}, rha[4] = {rh.x, rh.y, rh.z, rh.w};
    float ca[4] = {cv.x, cv.y, cv.z, cv.w}, oa[4] = {ov.x, ov.y, ov.z, ov.w};
    float hv[4];
    u16x4 hhi, hlo;
    #pragma unroll
    for (int j = 0; j < 4; ++j) {
        hv[j] = oa[j] * tanhf(ca[j] + sigf(rca[j]) * rha[j]);
        u16 th, tl;
        split_bf(hv[j], th, tl);
        hhi[j] = th; hlo[j] = tl;
    }
    *(float4*)(h_out + (size_t)row * 256 + c0) = make_float4(hv[0], hv[1], hv[2], hv[3]);
    *(u16x4*)(A4hi + (size_t)row * 256 + c0) = hhi;
    *(u16x4*)(A4lo + (size_t)row * 256 + c0) = hlo;
}

// ---------------------------------------------------------------------------
// e3: k_out = tanh(+bk); e = sig(+be); a = tanh(+ba)
// ---------------------------------------------------------------------------
__global__ __launch_bounds__(256) void e3(
    const float* __restrict__ G4,
    const float* __restrict__ bk, const float* __restrict__ be,
    const float* __restrict__ ba,
    float* __restrict__ k_out, float* __restrict__ e_ws, float* __restrict__ a_ws)
{
    const int idx = blockIdx.x * 256 + threadIdx.x;   // 4096*64
    const int row = idx >> 6;
    const int c0  = (idx & 63) * 4;
    const float* g = G4 + (size_t)row * 768 + c0;
    float4 kv = *(const float4*)(g);
    float4 ev = *(const float4*)(g + 256);
    float4 av = *(const float4*)(g + 512);
    float4 bkv = *(const float4*)(bk + c0), bev = *(const float4*)(be + c0);
    float4 bav = *(const float4*)(ba + c0);
    float ka[4] = {kv.x, kv.y, kv.z, kv.w}, ea[4] = {ev.x, ev.y, ev.z, ev.w};
    float aa[4] = {av.x, av.y, av.z, av.w};
    float bka[4] = {bkv.x, bkv.y, bkv.z, bkv.w}, bea[4] = {bev.x, bev.y, bev.z, bev.w};
    float baa[4] = {bav.x, bav.y, bav.z, bav.w};
    float ko[4], eo[4], ao[4];
    #pragma unroll
    for (int j = 0; j < 4; ++j) {
        ko[j] = tanhf(ka[j] + bka[j]);
        eo[j] = sigf (ea[j] + bea[j]);
        ao[j] = tanhf(aa[j] + baa[j]);
    }
    *(float4*)(k_out + (size_t)row * 256 + c0) = make_float4(ko[0], ko[1], ko[2], ko[3]);
    *(float4*)(e_ws  + (size_t)row * 256 + c0) = make_float4(eo[0], eo[1], eo[2], eo[3]);
    *(float4*)(a_ws  + (size_t)row * 256 + c0) = make_float4(ao[0], ao[1], ao[2], ao[3]);
}

// ---------------------------------------------------------------------------
// K5: M_curr = M_prev*(1 - alpha*e) + alpha*a   (streaming, nt loads/stores)
// ---------------------------------------------------------------------------
__global__ __launch_bounds__(256) void k5_mup(
    const float* __restrict__ M, const float* __restrict__ alpha,
    const float* __restrict__ e, const float* __restrict__ a,
    float* __restrict__ Mout)
{
    const int b = blockIdx.x;
    const int t = threadIdx.x;
    __shared__ float sal[64];
    if (t < 64) sal[t] = alpha[b * NUMK + t];

    const int s4 = (t & 63) * 4;
    const int kr = t >> 6;
    const float4 e4 = *(const float4*)(e + b * NUMS + s4);
    const float4 a4 = *(const float4*)(a + b * NUMS + s4);
    __syncthreads();

    const float* Mb = M + (size_t)b * (NUMK * NUMS);
    float* Ob = Mout + (size_t)b * (NUMK * NUMS);
    #pragma unroll
    for (int j = 0; j < 16; ++j) {
        const int k = j * 4 + kr;
        const float al = sal[k];
        f32x4 m4 = __builtin_nontemporal_load((const f32x4*)(Mb + k * NUMS + s4));
        f32x4 o4;
        o4.x = m4.x * (1.0f - al * e4.x) + al * a4.x;
        o4.y = m4.y * (1.0f - al * e4.y) + al * a4.y;
        o4.z = m4.z * (1.0f - al * e4.z) + al * a4.z;
        o4.w = m4.w * (1.0f - al * e4.w) + al * a4.w;
        __builtin_nontemporal_store(o4, (f32x4*)(Ob + k * NUMS + s4));
    }
}

// ---------------------------------------------------------------------------
extern "C" void kernel_launch(void* const* d_in, const int* in_sizes, int n_in,
                              void* d_out, int out_size, void* d_ws, size_t ws_size,
                              hipStream_t stream)
{
    (void)in_sizes; (void)n_in; (void)out_size; (void)ws_size;

    const float* X      = (const float*)d_in[0];
    const float* h_prev = (const float*)d_in[1];
    const float* c_prev = (const float*)d_in[2];
    const float* M_prev = (const float*)d_in[3];
    const float* k_prev = (const float*)d_in[4];
    const float* Wf = (const float*)d_in[5];
    const float* Wt = (const float*)d_in[6];
    const float* Wi = (const float*)d_in[7];
    const float* Wo = (const float*)d_in[8];
    const float* bf = (const float*)d_in[9];
    const float* bt = (const float*)d_in[10];
    const float* bi = (const float*)d_in[11];
    const float* bo = (const float*)d_in[12];
    const float* Wk = (const float*)d_in[13];
    const float* bk = (const float*)d_in[14];
    const float* Wr = (const float*)d_in[15];
    const float* Wc = (const float*)d_in[16];
    const float* Wh = (const float*)d_in[17];
    const float* We = (const float*)d_in[18];
    const float* be = (const float*)d_in[19];
    const float* Wa = (const float*)d_in[20];
    const float* ba = (const float*)d_in[21];

    float* out = (float*)d_out;
    float* h_out = out;
    float* c_out = out + 1048576;
    float* M_out = out + 2097152;
    float* k_out = out + 69206016;

    // workspace carve-up (bytes, 256-aligned)
    char* w = (char*)d_ws;
    size_t off = 0;
    auto carve = [&](size_t bytes) { void* p = w + off; off += (bytes + 255) & ~(size_t)255; return p; };
    u16* A1hi = (u16*)carve(4096ull * 384 * 2);
    u16* A1lo = (u16*)carve(4096ull * 384 * 2);
    u16* W1hi = (u16*)carve(1024ull * 384 * 2);
    u16* W1lo = (u16*)carve(1024ull * 384 * 2);
    u16* W3hi = (u16*)carve(512ull * 512 * 2);
    u16* W3lo = (u16*)carve(512ull * 512 * 2);
    u16* W4hi = (u16*)carve(768ull * 256 * 2);
    u16* W4lo = (u16*)carve(768ull * 256 * 2);
    u16* A3hi = (u16*)carve(4096ull * 512 * 2);
    u16* A3lo = (u16*)carve(4096ull * 512 * 2);
    u16* A4hi = (u16*)carve(4096ull * 256 * 2);
    u16* A4lo = (u16*)carve(4096ull * 256 * 2);
    float* G1  = (float*)carve(4096ull * 1024 * 4);
    float* G3  = (float*)carve(4096ull * 512 * 4);
    float* G4  = (float*)carve(4096ull * 768 * 4);
    float* o_ws  = (float*)carve(4096ull * 256 * 4);
    float* al_ws = (float*)carve(4096ull * 64 * 4);
    float* e_ws  = (float*)carve(4096ull * 256 * 4);
    float* a_ws  = (float*)carve(4096ull * 256 * 4);

    // prep (packs are cheap; run every call)
    pack_w1<<<192, 256, 0, stream>>>(Wf, Wt, Wi, Wo, W1hi, W1lo);
    pack_w3<<<128, 256, 0, stream>>>(Wr, Wc, Wh, W3hi, W3lo);
    pack_w4<<<96, 256, 0, stream>>>(Wk, We, Wa, W4hi, W4lo);
    prep_a1<<<1536, 256, 0, stream>>>(X, h_prev, A1hi, A1lo);

    // cos/softmax/r (independent of gates) — fills A3 r-half
    k2_cosr<<<4096, 256, 0, stream>>>(M_prev, k_prev, al_ws, A3hi, A3lo);

    // gates GEMM + epilogue -> c, o, A3 c-half
    gemm_bf16x2<384><<<dim3(64, 16), 256, 0, stream>>>(A1hi, A1lo, W1hi, W1lo, G1, 1024);
    e1<<<1024, 256, 0, stream>>>(G1, c_prev, bf, bt, bi, bo, c_out, A3hi, A3lo, o_ws);

    // [r|c] GEMM + epilogue -> h, A4
    gemm_bf16x2<512><<<dim3(64, 8), 256, 0, stream>>>(A3hi, A3lo, W3hi, W3lo, G3, 512);
    e2<<<1024, 256, 0, stream>>>(G3, c_out, o_ws, h_out, A4hi, A4lo);

    // h GEMM + epilogue -> k_out, e, a
    gemm_bf16x2<256><<<dim3(64, 12), 256, 0, stream>>>(A4hi, A4lo, W4hi, W4lo, G4, 768);
    e3<<<1024, 256, 0, stream>>>(G4, bk, be, ba, k_out, e_ws, a_ws);

    // M update
    k5_mup<<<4096, 256, 0, stream>>>(M_prev, al_ws, e_ws, a_ws, M_out);
}